// Round 14
// baseline (124.356 us; speedup 1.0000x reference)
//
#include <hip/hip_runtime.h>
#include <stdint.h>

#define Bd 8
#define Rr 5
#define Nn 1024
#define Dd 512

typedef __attribute__((ext_vector_type(8))) short bf16x8;
typedef __attribute__((ext_vector_type(4))) float f32x4;
typedef unsigned short u16;
typedef unsigned int u32;

__device__ __forceinline__ u16 f2bf(float x){
  union { float f; unsigned u; } v; v.f = x;
  unsigned r = v.u + 0x7FFFu + ((v.u >> 16) & 1u);
  return (u16)(r >> 16);
}

__device__ __forceinline__ void gll16(const void* g, void* l){
  __builtin_amdgcn_global_load_lds(
      (const __attribute__((address_space(1))) void*)g,
      (__attribute__((address_space(3))) void*)l, 16, 0, 0);
}

// ---------------- KC: h -> hb bf16 flat; W -> Wb bf16 flat ----------------
__global__ __launch_bounds__(256) void kc(
    const float* __restrict__ h, const float* __restrict__ W,
    u16* __restrict__ hb, u16* __restrict__ Wb){
  const int g = blockIdx.x, tid = threadIdx.x;
  const float* src; u16* dst; size_t idx;
  if (g < 2048){ idx = (size_t)g*2048 + tid*8; src = h; dst = hb; }
  else         { idx = (size_t)(g-2048)*2048 + tid*8; src = W; dst = Wb; }
  f32x4 a = *(const f32x4*)(src + idx);
  f32x4 c = *(const f32x4*)(src + idx + 4);
  bf16x8 pk;
  pk[0]=(short)f2bf(a.x); pk[1]=(short)f2bf(a.y);
  pk[2]=(short)f2bf(a.z); pk[3]=(short)f2bf(a.w);
  pk[4]=(short)f2bf(c.x); pk[5]=(short)f2bf(c.y);
  pk[6]=(short)f2bf(c.z); pk[7]=(short)f2bf(c.w);
  *(bf16x8*)(dst + idx) = pk;
}

// ---------------- K_GR: G_r[b][u][e] = sum_d h[b][u][d] W_r[e][d] ----------
// k_agg-clone: block tile 64 e x 128 u, K=512, 8 waves (wm2 x wn4) 32x32.
// Output packed fragment-major: Gp[b][gut(u>>5)][get=r*32+(e>>4)][er][uu].
__global__ __launch_bounds__(512,4) void k_gr(
    const u16* __restrict__ hb, const u16* __restrict__ Wb,
    u16* __restrict__ Gp){
  __shared__ __align__(16) u16 sA[2][64*64];
  __shared__ __align__(16) u16 sB[2][128*64];
  const int tid = threadIdx.x;
  const int lane = tid & 63, wave = tid >> 6;
  const int wm = wave >> 2, wn = wave & 3;
  const int g = blockIdx.x;
  const int utb = g & 7;
  const int etb = (g >> 3) & 7;
  const int br = g >> 6;
  const int r = br % 5;
  const int b = br / 5;
  const u16* Ab = Wb + ((size_t)r*512 + etb*64)*512;
  const u16* Bb = hb + ((size_t)b*1024 + utb*128)*512;

  f32x4 acc[2][2];
  #pragma unroll
  for (int m=0;m<2;m++)
    #pragma unroll
    for (int n=0;n<2;n++) acc[m][n] = (f32x4){0.f,0.f,0.f,0.f};

  #define STAGE(buf, kt) do {                                              \
    { int c = tid; int row_ = c>>3, chg = (c&7) ^ (row_&7);                \
      gll16(Ab + (size_t)row_*512 + (kt)*64 + chg*8,                       \
            (char*)sA[buf] + ((size_t)(wave<<6))*16); }                    \
    _Pragma("unroll")                                                      \
    for (int i=0;i<2;i++){                                                 \
      int c = i*512 + tid; int row_ = c>>3, chg = (c&7) ^ (row_&7);        \
      gll16(Bb + (size_t)row_*512 + (kt)*64 + chg*8,                       \
            (char*)sB[buf] + ((size_t)(i*512 + (wave<<6)))*16);            \
    }                                                                      \
  } while(0)

  STAGE(0, 0);
  __syncthreads();

  const int ch = lane >> 4, rlo = lane & 15;

  for (int kt = 0; kt < 8; ++kt){
    if (kt < 7) STAGE((kt+1)&1, kt+1);
    const char* a  = (const char*)sA[kt&1];
    const char* bb = (const char*)sB[kt&1];
    #pragma unroll
    for (int kk=0; kk<2; ++kk){
      bf16x8 af[2], bfx[2];
      #pragma unroll
      for (int m=0;m<2;m++){
        const int row = wm*32 + m*16 + rlo;
        af[m] = *(const bf16x8*)(a + row*128 + ((((kk<<2)+ch) ^ (row&7))<<4));
      }
      #pragma unroll
      for (int n=0;n<2;n++){
        const int row = wn*32 + n*16 + rlo;
        bfx[n] = *(const bf16x8*)(bb + row*128 + ((((kk<<2)+ch) ^ (row&7))<<4));
      }
      #pragma unroll
      for (int m=0;m<2;m++)
        #pragma unroll
        for (int n=0;n<2;n++)
          acc[m][n] = __builtin_amdgcn_mfma_f32_16x16x32_bf16(af[m], bfx[n], acc[m][n], 0, 0, 0);
    }
    __syncthreads();
  }
  #undef STAGE

  // store packed: e = A-row, u = B-col
  #pragma unroll
  for (int m=0;m<2;m++)
    #pragma unroll
    for (int reg=0;reg<4;reg++){
      const int e = etb*64 + wm*32 + m*16 + ((lane>>4)<<2) + reg;
      #pragma unroll
      for (int n=0;n<2;n++){
        const int u = utb*128 + wn*32 + n*16 + (lane & 15);
        Gp[(((size_t)b*32 + (u>>5))*160 + r*32 + (e>>4))*512
           + (size_t)((e&15)*32 + (u&31))] = f2bf(acc[m][n][reg]);
      }
    }
}

// ---------------- K_FUSE: out = LN(relu(G0 + sum_r D^-1 adj_r G_r) + h) ----
// 1024 thr = 16 waves, BM=32 v, wave owns 32 e. adj via gll depth-2 (sF32
// wave-private regions), PACK f32->bf16 sA; G_r fragments inline from Gp.
__global__ __launch_bounds__(1024,4) void k_fuse(
    const float* __restrict__ adj, const u16* __restrict__ Gp,
    const float* __restrict__ h, const float* __restrict__ gamma,
    const float* __restrict__ beta, float* __restrict__ out){
  // [0,98304) sF32 3x32KB (overlaid by sT 33KB later); [98304,131072) sA 2x16KB
  __shared__ __align__(16) char smem[131584];
  char* sAc = smem + 98304;
  float (*sDeg)[32] = (float(*)[32])(smem + 131072);
  float* sT = (float*)smem;

  const int tid  = threadIdx.x;
  const int lane = tid & 63;
  const int wave = tid >> 6;          // 0..15
  const int b  = blockIdx.x & 7;      // b -> XCD
  const int vt = blockIdx.x >> 3;     // 0..31
  const int v0 = vt * 32;
  const int t0 = blockIdx.x & 15;
  const float* adjb = adj + (((size_t)b*Rr + 1)*Nn + v0)*Nn;  // r=1 base
  const u16* Gpb = Gp + (size_t)b*32*160*512;

  // PACK roles (thread-local decode of the gll-linear sF32 layout)
  const int pari  = tid >> 8;                          // 0..3 relation
  const int psrow = ((tid>>5)&7)*4 + ((tid&31)>>3);    // 0..31 v-row
  const int psc   = tid & 7;                           // 8-f32 u chunk
  const int pwslot = psc ^ (psrow & 7);

  const int rlo = lane & 15, ch = lane >> 4;
  const int boff = rlo*32 + ch*8;

  float deg = 0.f;
  f32x4 accr[4][2][2];
  f32x4 acct[2][2];
  #pragma unroll
  for (int ri=0;ri<4;ri++)
    #pragma unroll
    for (int m=0;m<2;m++)
      #pragma unroll
      for (int n=0;n<2;n++) accr[ri][m][n] = (f32x4){0.f,0.f,0.f,0.f};

  // relation-0 (identity) shortcut: acct = G_0 fragment (deg=1)
  #pragma unroll
  for (int m=0;m<2;m++)
    #pragma unroll
    for (int n=0;n<2;n++)
      #pragma unroll
      for (int reg=0;reg<4;reg++){
        u16 gv = Gpb[((size_t)vt*160 + (wave*2+m))*512 + (ch*4+reg)*32 + n*16 + rlo];
        acct[m][n][reg] = __uint_as_float((u32)gv << 16);
      }

  #define TT(x) (((x) + t0) & 15)

  // wave w glls its own 2KB region: g = 2w+s -> (ari=g>>3, rowgrp=g&7)
  #define GLLA(T) do {                                                        \
    char* _d = smem + ((T)%3)*32768 + (size_t)wave*2048;                      \
    _Pragma("unroll")                                                         \
    for (int s_=0;s_<2;s_++){                                                 \
      const int g_ = wave*2 + s_;                                             \
      gll16(adjb + (size_t)(g_>>3)*Nn*Nn                                      \
                 + (size_t)((g_&7)*4 + (lane>>4))*Nn + TT(T)*64 + (lane&15)*4,\
            _d + s_*1024);                                                    \
    }                                                                         \
  } while(0)

  // PACK tile T: read OWN 32B of sF32[T%3], convert, write sA[T&1]
  #define PACKL(T) do {                                                      \
    const float* _s = (const float*)(smem + ((T)%3)*32768 + (size_t)tid*32);  \
    f32x4 p0 = *(const f32x4*)_s;                                             \
    f32x4 p1 = *(const f32x4*)(_s + 4);                                       \
    deg += p0.x+p0.y+p0.z+p0.w + p1.x+p1.y+p1.z+p1.w;                         \
    uint4 pk;  /* adj in {0,1}: truncation exact */                           \
    pk.x = (__float_as_uint(p0.x)>>16) | (__float_as_uint(p0.y) & 0xFFFF0000u);\
    pk.y = (__float_as_uint(p0.z)>>16) | (__float_as_uint(p0.w) & 0xFFFF0000u);\
    pk.z = (__float_as_uint(p1.x)>>16) | (__float_as_uint(p1.y) & 0xFFFF0000u);\
    pk.w = (__float_as_uint(p1.z)>>16) | (__float_as_uint(p1.w) & 0xFFFF0000u);\
    *(uint4*)(sAc + ((T)&1)*16384 + pari*4096 + psrow*128 + (pwslot<<4)) = pk; \
  } while(0)

  // accr[ri][m][n] += G_{ri+1}[e][u] x adj_{ri+1}[u][v]; G inline from Gp
  #define MSTEP(T) do {                                                       \
    const char* abase = sAc + ((T)&1)*16384;                                  \
    _Pragma("unroll")                                                         \
    for (int kk=0;kk<2;kk++){                                                 \
      const size_t gut_ = (size_t)(TT(T)*2 + kk);                             \
      _Pragma("unroll")                                                       \
      for (int ri=0;ri<4;ri++){                                               \
        const u16* gp = Gpb + (gut_*160 + (ri+1)*32 + wave*2)*512 + boff;     \
        bf16x8 aG0 = *(const bf16x8*)gp;                                      \
        bf16x8 aG1 = *(const bf16x8*)(gp + 512);                              \
        bf16x8 bv0 = *(const bf16x8*)(abase + ri*4096 + rlo*128               \
                      + (((kk*4+ch) ^ (rlo&7))<<4));                          \
        bf16x8 bv1 = *(const bf16x8*)(abase + ri*4096 + (16+rlo)*128          \
                      + (((kk*4+ch) ^ (rlo&7))<<4));                          \
        accr[ri][0][0] = __builtin_amdgcn_mfma_f32_16x16x32_bf16(aG0, bv0, accr[ri][0][0], 0,0,0); \
        accr[ri][0][1] = __builtin_amdgcn_mfma_f32_16x16x32_bf16(aG0, bv1, accr[ri][0][1], 0,0,0); \
        accr[ri][1][0] = __builtin_amdgcn_mfma_f32_16x16x32_bf16(aG1, bv0, accr[ri][1][0], 0,0,0); \
        accr[ri][1][1] = __builtin_amdgcn_mfma_f32_16x16x32_bf16(aG1, bv1, accr[ri][1][1], 0,0,0); \
      }                                                                       \
    }                                                                         \
  } while(0)

  #define FENCE() __builtin_amdgcn_sched_barrier(0)
  #define STEP_BARRIER() do {                                                 \
    asm volatile("s_waitcnt lgkmcnt(0)" ::: "memory");                        \
    FENCE();                                                                  \
    __builtin_amdgcn_s_barrier();                                             \
    FENCE();                                                                  \
  } while(0)

  // prologue
  GLLA(0);
  GLLA(1);
  asm volatile("s_waitcnt vmcnt(2)" ::: "memory");   // own gll(0) landed
  FENCE();
  PACKL(0);                                          // own region only
  __syncthreads();                                   // publish sA[0]

  for (int t = 0; t < 15; ++t){
    MSTEP(t);            // G-waits retire own gll(t+1)
    FENCE();
    if (t < 14) GLLA(t+2);
    FENCE();
    PACKL(t+1);          // own gll(t+1) retired above
    STEP_BARRIER();      // publish sA[(t+1)&1]; gll(t+2) stays in flight
  }
  MSTEP(15);
  #undef TT
  #undef GLLA
  #undef PACKL
  #undef MSTEP

  // deg reduce over 8 threads sharing (pari,psrow) = lane bits 0..2
  {
    float d = deg;
    d += __shfl_xor(d, 1); d += __shfl_xor(d, 2); d += __shfl_xor(d, 4);
    if (psc == 0) sDeg[pari][psrow] = d;
  }
  __syncthreads();

  // fold relations into acct with 1/deg scaling
  #pragma unroll
  for (int ri=0;ri<4;ri++)
    #pragma unroll
    for (int n=0;n<2;n++){
      const float inv = 1.0f / fmaxf(sDeg[ri][n*16 + rlo], 1.0f);
      #pragma unroll
      for (int m=0;m<2;m++)
        #pragma unroll
        for (int reg=0;reg<4;reg++)
          acct[m][n][reg] += accr[ri][m][n][reg] * inv;
    }
  __syncthreads();   // sF32 dead -> sT reuse safe

  // phase 3: relu -> sT transpose -> +h residual -> LN -> out (2 halves)
  #pragma unroll
  for (int n=0; n<2; ++n){
    #pragma unroll
    for (int m=0;m<2;m++)
      #pragma unroll
      for (int reg=0;reg<4;reg++){
        const int e = wave*32 + m*16 + ch*4 + reg;
        const int colw = e ^ (((e>>5)&7)<<2);
        sT[rlo*516 + colw] = fmaxf(acct[m][n][reg], 0.f);
      }
    __syncthreads();
    {
      const int grow = v0 + n*16 + wave;    // wave handles one LN row
      const float* hp = h + ((size_t)b*Nn + grow)*Dd + lane*8;
      float x[8];
      float sum = 0.f, sq = 0.f;
      #pragma unroll
      for (int j=0;j<2;j++){
        const int col = lane*8 + j*4;
        const int colw = col ^ (((col>>5)&7)<<2);
        f32x4 sv = *(const f32x4*)&sT[wave*516 + colw];
        f32x4 hv = *(const f32x4*)(hp + j*4);
        #pragma unroll
        for (int k=0;k<4;k++){
          float val = sv[k] + hv[k];
          x[j*4+k] = val; sum += val; sq += val*val;
        }
      }
      #pragma unroll
      for (int off=32; off; off>>=1){
        sum += __shfl_xor(sum, off);
        sq  += __shfl_xor(sq,  off);
      }
      const float mu  = sum * (1.f/(float)Dd);
      const float var = sq * (1.f/(float)Dd) - mu*mu;
      const float rstd = rsqrtf(var + 1e-5f);
      float* op = out + ((size_t)b*Nn + grow)*Dd + lane*8;
      #pragma unroll
      for (int j=0;j<2;j++){
        f32x4 g  = *(const f32x4*)(gamma + lane*8 + j*4);
        f32x4 be = *(const f32x4*)(beta  + lane*8 + j*4);
        f32x4 ov;
        #pragma unroll
        for (int k=0;k<4;k++)
          ov[k] = (x[j*4+k] - mu) * rstd * g[k] + be[k];
        *(f32x4*)(op + j*4) = ov;
      }
    }
    __syncthreads();
  }
  #undef FENCE
  #undef STEP_BARRIER
}

extern "C" void kernel_launch(void* const* d_in, const int* in_sizes, int n_in,
                              void* d_out, int out_size, void* d_ws, size_t ws_size,
                              hipStream_t stream){
  const float* h     = (const float*)d_in[0];
  const float* adj   = (const float*)d_in[1];
  const float* W     = (const float*)d_in[2];
  const float* gamma = (const float*)d_in[3];
  const float* beta  = (const float*)d_in[4];
  float* out = (float*)d_out;
  char* ws = (char*)d_ws;

  u16* hb = (u16*)(ws);                  //  8,388,608  (Bd*Nn*Dd*2)
  u16* Wb = (u16*)(ws + 8388608);        //  2,621,440  (Rr*Dd*Dd*2)
  u16* Gp = (u16*)(ws + 11010048);       // 41,943,040  (Bd*32*160*512*2)

  kc    <<<dim3(2688), dim3(256), 0, stream>>>(h, W, hb, Wb);
  k_gr  <<<dim3(2560), dim3(512), 0, stream>>>(hb, Wb, Gp);
  k_fuse<<<dim3(Bd*32), dim3(1024), 0, stream>>>(adj, Gp, h, gamma, beta, out);
}

// Round 15
// 99.520 us; speedup vs baseline: 1.2496x; 1.2496x over previous
//
#include <hip/hip_runtime.h>
#include <stdint.h>

#define Bd 8
#define Rr 5
#define Nn 1024
#define Dd 512
#define KK (Rr*Dd) /* 2560 */

typedef __attribute__((ext_vector_type(8))) short bf16x8;
typedef __attribute__((ext_vector_type(4))) float f32x4;
typedef unsigned short u16;
typedef unsigned int u32;

__device__ __forceinline__ u16 f2bf(float x){
  union { float f; unsigned u; } v; v.f = x;
  unsigned r = v.u + 0x7FFFu + ((v.u >> 16) & 1u);
  return (u16)(r >> 16);
}

__device__ __forceinline__ void gll16(const void* g, void* l){
  __builtin_amdgcn_global_load_lds(
      (const __attribute__((address_space(1))) void*)g,
      (__attribute__((address_space(3))) void*)l, 16, 0, 0);
}

// ---------------- K1: fused prep ----------------
// g < 2048:          hTp fragment-major pack of h
// g in [2048,3328):  Wt2p[kt][et][er][kk] packed W (k<2048: r=1+k/512; else r=0)
// g >= 3328:         msg[row][2048+d] = bf16 h[row][d] (identity relation)
__global__ __launch_bounds__(256) void k_prep(
    const float* __restrict__ h, const float* __restrict__ W,
    u16* __restrict__ hTp, u16* __restrict__ Wt2p, u16* __restrict__ msg){
  __shared__ float t32[32][65];
  const int tid = threadIdx.x;
  const int g = blockIdx.x;
  if (g < 2048){
    const int ut  = g & 31;
    const int dtg = (g >> 5) & 7;
    const int b   = g >> 8;
    const float* hb = h + ((size_t)b*Nn + (size_t)ut*32)*Dd + dtg*64;
    #pragma unroll
    for (int j=0;j<8;j++){
      int e = j*256 + tid;
      int ul = e >> 6, dl = e & 63;
      t32[ul][dl] = hb[(size_t)ul*Dd + dl];
    }
    __syncthreads();
    u16* ob = hTp + (size_t)b*Dd*Nn;
    #pragma unroll
    for (int j=0;j<8;j++){
      int e = j*256 + tid;
      int dtl = e >> 9;
      int rem = e & 511;
      int dr = rem >> 5, uu = rem & 31;
      int dt = dtg*4 + dtl;
      ob[((size_t)ut*32 + dt)*512 + rem] = f2bf(t32[uu][dtl*16 + dr]);
    }
  } else if (g < 3328){
    int q = (g - 2048)*1024 + tid*4;       // over 512*2560, 4 u16 along kk
    int kk = q & 31;
    int er = (q >> 5) & 15;
    int et = (q >> 9) & 31;
    int kt = q >> 14;
    int k = kt*32 + kk;
    int e = et*16 + er;
    int r, d;
    if (k < 2048){ r = 1 + (k >> 9); d = k & 511; }
    else         { r = 0;            d = k - 2048; }
    f32x4 w = *(const f32x4*)(W + (((size_t)r*Dd + e)*Dd + d));
    u16 o[4] = { f2bf(w.x), f2bf(w.y), f2bf(w.z), f2bf(w.w) };
    *(uint2*)(Wt2p + q) = *(uint2*)o;
  } else {
    int q = g - 3328;                      // 0..2047
    int row = q*4 + (tid >> 6);
    int d0 = (tid & 63)*8;
    f32x4 a = *(const f32x4*)(h + (size_t)row*Dd + d0);
    f32x4 c = *(const f32x4*)(h + (size_t)row*Dd + d0 + 4);
    bf16x8 pk;
    pk[0]=(short)f2bf(a.x); pk[1]=(short)f2bf(a.y);
    pk[2]=(short)f2bf(a.z); pk[3]=(short)f2bf(a.w);
    pk[4]=(short)f2bf(c.x); pk[5]=(short)f2bf(c.y);
    pk[6]=(short)f2bf(c.z); pk[7]=(short)f2bf(c.w);
    *(bf16x8*)(msg + (size_t)row*KK + 2048 + d0) = pk;
  }
}

// ---------------- K2: r-fused msg (R9 verbatim, the 92us bank) ----------------
__global__ __launch_bounds__(512,2) void k_msg(
    const float* __restrict__ adj, const u16* __restrict__ hTp,
    u16* __restrict__ msg){
  __shared__ __align__(16) u16 sA[2][4][32*64];   // 32KB double-buffered adj
  __shared__ float sT[16*516];                    // 33KB epilogue transpose
  __shared__ float sDeg[4][32];

  const int tid  = threadIdx.x;
  const int lane = tid & 63;
  const int wave = tid >> 6;
  const int b  = blockIdx.x & 7;     // b -> XCD (L2 locality for hTp[b])
  const int vt = blockIdx.x >> 3;
  const int v0 = vt * 32;
  const int t0 = blockIdx.x & 15;    // stagger
  const float* adjb = adj + (((size_t)b*Rr + 1)*Nn + v0)*Nn;  // r=1 base
  const u16* hTpb = hTp + (size_t)b*Dd*Nn;

  const int srow = tid >> 4;         // 0..31
  const int sc   = tid & 15;         // 16B chunk
  const size_t aoff = (size_t)srow*Nn + sc*4;
  const int wslot = sc ^ ((srow & 7) << 1);

  float deg[4] = {0.f,0.f,0.f,0.f};
  f32x4 areg[4];
  f32x4 acc[4][2][4];
  #pragma unroll
  for (int ri=0;ri<4;ri++)
    #pragma unroll
    for (int m=0;m<2;m++)
      #pragma unroll
      for (int n=0;n<4;n++) acc[ri][m][n] = (f32x4){0.f,0.f,0.f,0.f};

  const int rlo = lane & 15, ch = lane >> 4;
  const int boff = rlo*32 + ch*8;

  #define TT(x) (((x) + t0) & 15)

  #define AISSUE(T) do {                                                      \
    _Pragma("unroll")                                                         \
    for (int ri=0;ri<4;ri++)                                                  \
      areg[ri] = *(const f32x4*)(adjb + (size_t)ri*Nn*Nn + (size_t)(T)*64 + aoff); \
  } while(0)

  #define PACK(BUFI) do {                                                     \
    _Pragma("unroll")                                                         \
    for (int ri=0;ri<4;ri++){                                                 \
      f32x4 p = areg[ri];                                                     \
      deg[ri] += p.x+p.y+p.z+p.w;                                             \
      uint2 pk;  /* adj in {0,1}: truncation exact */                         \
      pk.x = (__float_as_uint(p.x)>>16) | (__float_as_uint(p.y) & 0xFFFF0000u);\
      pk.y = (__float_as_uint(p.z)>>16) | (__float_as_uint(p.w) & 0xFFFF0000u);\
      *(uint2*)((char*)sA[BUFI][ri] + srow*128 + wslot*8) = pk;               \
    }                                                                         \
  } while(0)

  #define LOADB(T) do {                                                      \
    _Pragma("unroll")                                                         \
    for (int kk=0;kk<2;kk++){                                                 \
      const u16* bp = hTpb + ((((size_t)((T)*2+kk))*32 + (wave<<2))<<9) + boff;\
      _Pragma("unroll")                                                       \
      for (int n=0;n<4;n++)                                                   \
        bfr[kk][n] = *(const bf16x8*)(bp + ((size_t)n<<9));                   \
    }                                                                         \
  } while(0)

  #define MSTEP(BUFI) do {                                                    \
    const char* abase = (const char*)sA[BUFI];                                \
    _Pragma("unroll")                                                         \
    for (int kk=0;kk<2;kk++){                                                 \
      _Pragma("unroll")                                                       \
      for (int ri=0;ri<4;ri++){                                               \
        bf16x8 af[2];                                                         \
        _Pragma("unroll")                                                     \
        for (int m=0;m<2;m++){                                                \
          const int row = m*16 + rlo;                                         \
          af[m] = *(const bf16x8*)(abase + ri*4096 + row*128                  \
                    + (((kk*8 + ch*2) ^ ((row&7)<<1))<<3));                   \
        }                                                                     \
        _Pragma("unroll")                                                     \
        for (int m=0;m<2;m++)                                                 \
          _Pragma("unroll")                                                   \
          for (int n=0;n<4;n++)                                               \
            acc[ri][m][n] = __builtin_amdgcn_mfma_f32_16x16x32_bf16(          \
                af[m], bfr[kk][n], acc[ri][m][n], 0, 0, 0);                   \
      }                                                                       \
    }                                                                         \
  } while(0)

  #define FENCE() __builtin_amdgcn_sched_barrier(0)
  #define STEP_BARRIER() do {                                                 \
    asm volatile("s_waitcnt lgkmcnt(0)" ::: "memory");                        \
    FENCE();                                                                  \
    __builtin_amdgcn_s_barrier();                                             \
    FENCE();                                                                  \
  } while(0)

  bf16x8 bfr[2][4];

  // prologue
  AISSUE(TT(0));
  PACK(0);
  __syncthreads();
  LOADB(TT(0));
  FENCE();
  AISSUE(TT(1));
  FENCE();

  for (int t = 0; t < 15; ++t){
    PACK((t+1)&1);
    FENCE();
    if (t < 14) AISSUE(TT(t+2));
    FENCE();
    MSTEP(t&1);
    FENCE();
    LOADB(TT(t+1));
    STEP_BARRIER();
  }
  MSTEP(1);                    // t = 15
  #undef TT
  #undef AISSUE
  #undef PACK
  #undef LOADB
  #undef MSTEP
  #undef FENCE
  #undef STEP_BARRIER

  // deg reduce over the 16 threads sharing srow
  #pragma unroll
  for (int ri=0;ri<4;ri++){
    float d = deg[ri];
    d += __shfl_xor(d, 1); d += __shfl_xor(d, 2);
    d += __shfl_xor(d, 4); d += __shfl_xor(d, 8);
    if (sc == 0) sDeg[ri][srow] = d;
  }
  __syncthreads();

  // Epilogue: per ri: scale -> swizzled sT -> dense 1KB-row stores
  u16* mb = msg + ((size_t)b*Nn + v0)*KK;
  #pragma unroll
  for (int ri=0;ri<4;ri++){
    #pragma unroll
    for (int hh=0;hh<2;hh++){
      #pragma unroll
      for (int reg=0;reg<4;reg++){
        const int rl = ch*4 + reg;
        const float inv = 1.0f / fmaxf(sDeg[ri][hh*16 + rl], 1.0f);
        #pragma unroll
        for (int n=0;n<4;n++){
          const int col = (wave<<6) + n*16 + rlo;
          const int colw = col ^ (((col>>5)&7)<<2);
          sT[rl*516 + colw] = acc[ri][hh][n][reg] * inv;
        }
      }
      __syncthreads();
      #pragma unroll
      for (int s=0;s<2;s++){
        const int rl = wave*2 + s;
        const int m5 = lane >> 2;
        const int e  = m5 & 7;
        const int j0 = (2*lane) & 7;
        f32x4 lo = *(const f32x4*)&sT[rl*516 + (m5<<5) + (((j0  ) ^ e)<<2)];
        f32x4 hi = *(const f32x4*)&sT[rl*516 + (m5<<5) + (((j0+1) ^ e)<<2)];
        bf16x8 pk;
        pk[0]=(short)f2bf(lo.x); pk[1]=(short)f2bf(lo.y);
        pk[2]=(short)f2bf(lo.z); pk[3]=(short)f2bf(lo.w);
        pk[4]=(short)f2bf(hi.x); pk[5]=(short)f2bf(hi.y);
        pk[6]=(short)f2bf(hi.z); pk[7]=(short)f2bf(hi.w);
        *(bf16x8*)(mb + (size_t)(hh*16 + rl)*KK + ri*512 + lane*8) = pk;
      }
      __syncthreads();
    }
  }
}

// ---------------- K3: fused agg + relu + residual + LN -> out ----------------
// out[b][v0+v][:] for 32 v-rows per block; BN=512 e (full row), K=2560.
// A (msg) gll-staged pre-swizzled 4KB tiles; B (Wt2p) cross-barrier reg
// prefetch; counted vmcnt(8) never drains. Epilogue = R10 phase-3 (proven).
__global__ __launch_bounds__(512,1) void k_agg2(
    const u16* __restrict__ msg, const u16* __restrict__ Wt2p,
    const float* __restrict__ h, const float* __restrict__ gamma,
    const float* __restrict__ beta, float* __restrict__ out){
  __shared__ __align__(16) u16 sA[2][32*64];   // 2 x 4KB msg tiles (swizzled)
  __shared__ float sT[16*516];                 // 33KB transpose/LN buffer
  const int tid = threadIdx.x;
  const int lane = tid & 63;
  const int wave = tid >> 6;        // 0..7, owns e in [wave*64, wave*64+64)
  const int b  = blockIdx.x & 7;    // b -> XCD
  const int vt = blockIdx.x >> 3;   // 0..31
  const int v0 = vt * 32;
  const u16* Ab = msg + ((size_t)b*Nn + v0)*KK;
  const int rlo = lane & 15, ch = lane >> 4;
  const int boff = rlo*32 + ch*8;

  f32x4 acc2[4][2];                 // [m: e-16tile][n: v-16tile]
  #pragma unroll
  for (int m=0;m<4;m++)
    #pragma unroll
    for (int n=0;n<2;n++) acc2[m][n] = (f32x4){0.f,0.f,0.f,0.f};

  // A stage: waves 0..3, 1 gll/lane: chunk c = wave*64+lane (0..255)
  #define STAGE(buf, kt) do {                                                 \
    if (wave < 4){                                                            \
      int c = (wave<<6) + lane;                                               \
      int row_ = c>>3, chg = (c&7) ^ (row_&7);                                \
      gll16(Ab + (size_t)row_*KK + (size_t)(kt)*64 + chg*8,                   \
            (char*)sA[buf] + (wave<<10));                                     \
    }                                                                         \
  } while(0)

  #define LOADW(T) do {                                                      \
    _Pragma("unroll")                                                         \
    for (int kk=0;kk<2;kk++){                                                 \
      const size_t kt_ = (size_t)(T)*2 + kk;                                  \
      _Pragma("unroll")                                                       \
      for (int m=0;m<4;m++)                                                   \
        wfr[kk][m] = *(const bf16x8*)(Wt2p + ((kt_*32 + (wave<<2)+m)<<9) + boff);\
    }                                                                         \
  } while(0)

  #define MSTEP(BUFI) do {                                                    \
    const char* a = (const char*)sA[BUFI];                                    \
    _Pragma("unroll")                                                         \
    for (int kk=0;kk<2;kk++){                                                 \
      bf16x8 btf[2];                                                          \
      _Pragma("unroll")                                                       \
      for (int n=0;n<2;n++){                                                  \
        const int row = n*16 + rlo;                                           \
        btf[n] = *(const bf16x8*)(a + row*128 + ((((kk<<2)+ch) ^ (row&7))<<4)); \
      }                                                                       \
      _Pragma("unroll")                                                       \
      for (int m=0;m<4;m++)                                                   \
        _Pragma("unroll")                                                     \
        for (int n=0;n<2;n++)                                                 \
          acc2[m][n] = __builtin_amdgcn_mfma_f32_16x16x32_bf16(               \
              wfr[kk][m], btf[n], acc2[m][n], 0, 0, 0);                       \
    }                                                                         \
  } while(0)

  #define FENCE() __builtin_amdgcn_sched_barrier(0)
  #define STEP_BARRIER() do {                                                 \
    asm volatile("s_waitcnt lgkmcnt(0) vmcnt(8)" ::: "memory");               \
    FENCE();                                                                  \
    __builtin_amdgcn_s_barrier();                                             \
    FENCE();                                                                  \
  } while(0)

  bf16x8 wfr[2][4];

  STAGE(0, 0);
  __syncthreads();          // drains gll(0)
  LOADW(0);
  FENCE();

  for (int t = 0; t < 39; ++t){
    STAGE((t+1)&1, t+1);    // gll(t+1) issued first (oldest)
    FENCE();
    MSTEP(t&1);             // waits W(t) only (vmcnt(1): gll(t+1) in flight)
    FENCE();
    LOADW(t+1);             // W(t+1) crosses barrier in registers
    STEP_BARRIER();         // vmcnt(8): retires gll(t+1), leaves W(t+1)
  }
  MSTEP(1);                 // t = 39
  #undef STAGE
  #undef LOADW
  #undef MSTEP

  // epilogue: relu -> sT (swizzled) -> +h residual -> LN -> out (2 v-halves)
  __syncthreads();
  #pragma unroll
  for (int hh=0; hh<2; ++hh){
    #pragma unroll
    for (int m=0;m<4;m++)
      #pragma unroll
      for (int reg=0;reg<4;reg++){
        const int col = (wave<<6) + m*16 + ch*4 + reg;   // e
        const int colw = col ^ (((col>>5)&7)<<2);
        sT[rlo*516 + colw] = fmaxf(acc2[m][hh][reg], 0.f);
      }
    __syncthreads();
    {
      const int row = wave*2 + (lane>>5);     // 0..15 (v within half)
      const int elane = lane & 31;
      const int grow = v0 + hh*16 + row;
      const float* hp = h + ((size_t)b*Nn + grow)*Dd + elane*16;
      float x[16];
      float sum = 0.f, sq = 0.f;
      #pragma unroll
      for (int j=0;j<4;j++){
        const int col = elane*16 + j*4;
        const int colw = col ^ (((col>>5)&7)<<2);
        f32x4 sv = *(const f32x4*)&sT[row*516 + colw];
        f32x4 hv = *(const f32x4*)(hp + j*4);
        #pragma unroll
        for (int k=0;k<4;k++){
          float val = sv[k] + hv[k];
          x[j*4+k] = val; sum += val; sq += val*val;
        }
      }
      #pragma unroll
      for (int off=16; off; off>>=1){
        sum += __shfl_xor(sum, off);
        sq  += __shfl_xor(sq,  off);
      }
      const float mu  = sum * (1.f/(float)Dd);
      const float var = sq * (1.f/(float)Dd) - mu*mu;
      const float rstd = rsqrtf(var + 1e-5f);
      float* op = out + ((size_t)b*Nn + grow)*Dd + elane*16;
      #pragma unroll
      for (int j=0;j<4;j++){
        f32x4 g  = *(const f32x4*)(gamma + elane*16 + j*4);
        f32x4 be = *(const f32x4*)(beta  + elane*16 + j*4);
        f32x4 ov;
        #pragma unroll
        for (int k=0;k<4;k++)
          ov[k] = (x[j*4+k] - mu) * rstd * g[k] + be[k];
        *(f32x4*)(op + j*4) = ov;
      }
    }
    __syncthreads();
  }
  #undef FENCE
  #undef STEP_BARRIER
}

extern "C" void kernel_launch(void* const* d_in, const int* in_sizes, int n_in,
                              void* d_out, int out_size, void* d_ws, size_t ws_size,
                              hipStream_t stream){
  const float* h     = (const float*)d_in[0];
  const float* adj   = (const float*)d_in[1];
  const float* W     = (const float*)d_in[2];
  const float* gamma = (const float*)d_in[3];
  const float* beta  = (const float*)d_in[4];
  float* out = (float*)d_out;
  char* ws = (char*)d_ws;

  u16*  hTp  = (u16*)(ws);                //  8,388,608  (Bd*Dd*Nn*2)
  u16*  Wt2p = (u16*)(ws + 8388608);      //  2,621,440  (Dd*KK*2)
  u16*  msg  = (u16*)(ws + 11010048);     // 41,943,040  (Bd*Nn*KK*2)

  k_prep<<<dim3(5376), dim3(256), 0, stream>>>(h, W, hTp, Wt2p, msg);
  k_msg <<<dim3(Bd*32), dim3(512), 0, stream>>>(adj, hTp, msg);
  k_agg2<<<dim3(Bd*32), dim3(512), 0, stream>>>(msg, Wt2p, h, gamma, beta, out);
}

// Round 16
// 95.240 us; speedup vs baseline: 1.3057x; 1.0449x over previous
//
#include <hip/hip_runtime.h>
#include <stdint.h>

#define Bd 8
#define Rr 5
#define Nn 1024
#define Dd 512
#define KK (Rr*Dd) /* 2560 */

typedef __attribute__((ext_vector_type(8))) short bf16x8;
typedef __attribute__((ext_vector_type(4))) float f32x4;
typedef unsigned short u16;
typedef unsigned int u32;

__device__ __forceinline__ u16 f2bf(float x){
  union { float f; unsigned u; } v; v.f = x;
  unsigned r = v.u + 0x7FFFu + ((v.u >> 16) & 1u);
  return (u16)(r >> 16);
}

__device__ __forceinline__ void gll16(const void* g, void* l){
  __builtin_amdgcn_global_load_lds(
      (const __attribute__((address_space(1))) void*)g,
      (__attribute__((address_space(3))) void*)l, 16, 0, 0);
}

// ---------------- K1: fused prep ----------------
__global__ __launch_bounds__(256) void k_prep(
    const float* __restrict__ h, const float* __restrict__ W,
    u16* __restrict__ hTp, u16* __restrict__ Wt2, u16* __restrict__ msg){
  __shared__ float t32[32][65];
  const int tid = threadIdx.x;
  const int g = blockIdx.x;
  if (g < 2048){
    const int ut  = g & 31;
    const int dtg = (g >> 5) & 7;
    const int b   = g >> 8;
    const float* hb = h + ((size_t)b*Nn + (size_t)ut*32)*Dd + dtg*64;
    #pragma unroll
    for (int j=0;j<8;j++){
      int e = j*256 + tid;
      int ul = e >> 6, dl = e & 63;
      t32[ul][dl] = hb[(size_t)ul*Dd + dl];
    }
    __syncthreads();
    u16* ob = hTp + (size_t)b*Dd*Nn;
    #pragma unroll
    for (int j=0;j<8;j++){
      int e = j*256 + tid;
      int dtl = e >> 9;
      int rem = e & 511;
      int dr = rem >> 5, uu = rem & 31;
      int dt = dtg*4 + dtl;
      ob[((size_t)ut*32 + dt)*512 + rem] = f2bf(t32[uu][dtl*16 + dr]);
    }
  } else if (g < 3328){
    int idx = (g - 2048)*1024 + tid*4;     // over 512*2560
    int e = idx / KK;
    int k = idx % KK;
    int ri = (k < 2048) ? (1 + (k >> 9)) : 0;
    int d = k & 511;
    f32x4 w = *(const f32x4*)(W + (((size_t)ri*Dd + e)*Dd + d));
    u16 o[4] = { f2bf(w.x), f2bf(w.y), f2bf(w.z), f2bf(w.w) };
    *(uint2*)(Wt2 + idx) = *(uint2*)o;
  } else {
    int q = g - 3328;                      // 0..2047
    int row = q*4 + (tid >> 6);
    int d0 = (tid & 63)*8;
    f32x4 a = *(const f32x4*)(h + (size_t)row*Dd + d0);
    f32x4 c = *(const f32x4*)(h + (size_t)row*Dd + d0 + 4);
    bf16x8 pk;
    pk[0]=(short)f2bf(a.x); pk[1]=(short)f2bf(a.y);
    pk[2]=(short)f2bf(a.z); pk[3]=(short)f2bf(a.w);
    pk[4]=(short)f2bf(c.x); pk[5]=(short)f2bf(c.y);
    pk[6]=(short)f2bf(c.z); pk[7]=(short)f2bf(c.w);
    *(bf16x8*)(msg + (size_t)row*KK + 2048 + d0) = pk;
  }
}

// ---------------- K2: r-fused msg, cross-barrier B prefetch (R9 verbatim) ----
// msg[b][v][(r-1)*512+d] = (1/deg) * sum_u adj[b,r,v,u] h[b,u,d]
// BM=32, BN=512, BK=64, 16 steps, grid 256 (1 block/CU), 512 thr = 8 waves.
__global__ __launch_bounds__(512,2) void k_msg(
    const float* __restrict__ adj, const u16* __restrict__ hTp,
    u16* __restrict__ msg){
  __shared__ __align__(16) u16 sA[2][4][32*64];   // 32KB double-buffered adj
  __shared__ float sT[16*516];                    // 33KB epilogue transpose
  __shared__ float sDeg[4][32];

  const int tid  = threadIdx.x;
  const int lane = tid & 63;
  const int wave = tid >> 6;
  const int b  = blockIdx.x & 7;     // b -> XCD (L2 locality for hTp[b])
  const int vt = blockIdx.x >> 3;
  const int v0 = vt * 32;
  const int t0 = blockIdx.x & 15;    // stagger
  const float* adjb = adj + (((size_t)b*Rr + 1)*Nn + v0)*Nn;  // r=1 base
  const u16* hTpb = hTp + (size_t)b*Dd*Nn;

  const int srow = tid >> 4;         // 0..31
  const int sc   = tid & 15;         // 16B chunk
  const size_t aoff = (size_t)srow*Nn + sc*4;
  const int wslot = sc ^ ((srow & 7) << 1);

  float deg[4] = {0.f,0.f,0.f,0.f};
  f32x4 areg[4];
  f32x4 acc[4][2][4];
  #pragma unroll
  for (int ri=0;ri<4;ri++)
    #pragma unroll
    for (int m=0;m<2;m++)
      #pragma unroll
      for (int n=0;n<4;n++) acc[ri][m][n] = (f32x4){0.f,0.f,0.f,0.f};

  const int rlo = lane & 15, ch = lane >> 4;
  const int boff = rlo*32 + ch*8;

  #define TT(x) (((x) + t0) & 15)

  #define AISSUE(T) do {                                                      \
    _Pragma("unroll")                                                         \
    for (int ri=0;ri<4;ri++)                                                  \
      areg[ri] = *(const f32x4*)(adjb + (size_t)ri*Nn*Nn + (size_t)(T)*64 + aoff); \
  } while(0)

  #define PACK(BUFI) do {                                                     \
    _Pragma("unroll")                                                         \
    for (int ri=0;ri<4;ri++){                                                 \
      f32x4 p = areg[ri];                                                     \
      deg[ri] += p.x+p.y+p.z+p.w;                                             \
      uint2 pk;  /* adj in {0,1}: truncation exact */                         \
      pk.x = (__float_as_uint(p.x)>>16) | (__float_as_uint(p.y) & 0xFFFF0000u);\
      pk.y = (__float_as_uint(p.z)>>16) | (__float_as_uint(p.w) & 0xFFFF0000u);\
      *(uint2*)((char*)sA[BUFI][ri] + srow*128 + wslot*8) = pk;               \
    }                                                                         \
  } while(0)

  #define LOADB(T) do {                                                      \
    _Pragma("unroll")                                                         \
    for (int kk=0;kk<2;kk++){                                                 \
      const u16* bp = hTpb + ((((size_t)((T)*2+kk))*32 + (wave<<2))<<9) + boff;\
      _Pragma("unroll")                                                       \
      for (int n=0;n<4;n++)                                                   \
        bfr[kk][n] = *(const bf16x8*)(bp + ((size_t)n<<9));                   \
    }                                                                         \
  } while(0)

  #define MSTEP(BUFI) do {                                                    \
    const char* abase = (const char*)sA[BUFI];                                \
    _Pragma("unroll")                                                         \
    for (int kk=0;kk<2;kk++){                                                 \
      _Pragma("unroll")                                                       \
      for (int ri=0;ri<4;ri++){                                               \
        bf16x8 af[2];                                                         \
        _Pragma("unroll")                                                     \
        for (int m=0;m<2;m++){                                                \
          const int row = m*16 + rlo;                                         \
          af[m] = *(const bf16x8*)(abase + ri*4096 + row*128                  \
                    + (((kk*8 + ch*2) ^ ((row&7)<<1))<<3));                   \
        }                                                                     \
        _Pragma("unroll")                                                     \
        for (int m=0;m<2;m++)                                                 \
          _Pragma("unroll")                                                   \
          for (int n=0;n<4;n++)                                               \
            acc[ri][m][n] = __builtin_amdgcn_mfma_f32_16x16x32_bf16(          \
                af[m], bfr[kk][n], acc[ri][m][n], 0, 0, 0);                   \
      }                                                                       \
    }                                                                         \
  } while(0)

  #define FENCE() __builtin_amdgcn_sched_barrier(0)
  #define STEP_BARRIER() do {                                                 \
    asm volatile("s_waitcnt lgkmcnt(0)" ::: "memory");                        \
    FENCE();                                                                  \
    __builtin_amdgcn_s_barrier();                                             \
    FENCE();                                                                  \
  } while(0)

  bf16x8 bfr[2][4];

  // prologue: pack tile TT(0) -> buf0; B(TT(0)) oldest in FIFO; adj(TT(1)) next
  AISSUE(TT(0));
  PACK(0);
  __syncthreads();
  LOADB(TT(0));
  FENCE();
  AISSUE(TT(1));
  FENCE();

  for (int t = 0; t < 15; ++t){
    PACK((t+1)&1);             // consumes adj(t+1); vmcnt wait leaves B in flight
    FENCE();
    if (t < 14) AISSUE(TT(t+2));  // adj(t+2): ~1 full step in flight
    FENCE();
    MSTEP(t&1);                // bfr loaded last step: no exposed B wait
    FENCE();
    LOADB(TT(t+1));            // B(t+1) crosses the barrier in registers
    STEP_BARRIER();
  }
  MSTEP(1);                    // t = 15
  #undef TT
  #undef AISSUE
  #undef PACK
  #undef LOADB
  #undef MSTEP
  #undef FENCE
  #undef STEP_BARRIER

  // deg reduce over the 16 threads sharing srow
  #pragma unroll
  for (int ri=0;ri<4;ri++){
    float d = deg[ri];
    d += __shfl_xor(d, 1); d += __shfl_xor(d, 2);
    d += __shfl_xor(d, 4); d += __shfl_xor(d, 8);
    if (sc == 0) sDeg[ri][srow] = d;
  }
  __syncthreads();

  // Epilogue: per (ri, half): scale -> swizzled sT -> dense 1KB-row stores
  u16* mb = msg + ((size_t)b*Nn + v0)*KK;
  #pragma unroll
  for (int ri=0;ri<4;ri++){
    #pragma unroll
    for (int hh=0;hh<2;hh++){
      #pragma unroll
      for (int reg=0;reg<4;reg++){
        const int rl = ch*4 + reg;
        const float inv = 1.0f / fmaxf(sDeg[ri][hh*16 + rl], 1.0f);
        #pragma unroll
        for (int n=0;n<4;n++){
          const int col = (wave<<6) + n*16 + rlo;
          const int colw = col ^ (((col>>5)&7)<<2);
          sT[rl*516 + colw] = acc[ri][hh][n][reg] * inv;
        }
      }
      __syncthreads();
      #pragma unroll
      for (int s=0;s<2;s++){
        const int rl = wave*2 + s;
        const int m5 = lane >> 2;
        const int e  = m5 & 7;
        const int j0 = (2*lane) & 7;
        f32x4 lo = *(const f32x4*)&sT[rl*516 + (m5<<5) + (((j0  ) ^ e)<<2)];
        f32x4 hi = *(const f32x4*)&sT[rl*516 + (m5<<5) + (((j0+1) ^ e)<<2)];
        bf16x8 pk;
        pk[0]=(short)f2bf(lo.x); pk[1]=(short)f2bf(lo.y);
        pk[2]=(short)f2bf(lo.z); pk[3]=(short)f2bf(lo.w);
        pk[4]=(short)f2bf(hi.x); pk[5]=(short)f2bf(hi.y);
        pk[6]=(short)f2bf(hi.z); pk[7]=(short)f2bf(hi.w);
        *(bf16x8*)(mb + (size_t)(hh*16 + rl)*KK + ri*512 + lane*8) = pk;
      }
      __syncthreads();
    }
  }
}

// ---------------- K3: agg[b][v][e] = sum_k msg[b][v][k] * Wt2[e][k], K=2560
// Block decode: et INNERMOST -> the 4 et-siblings sharing one msg panel are
// co-scheduled (panel fetched once into L2/L3 concurrently).
__global__ __launch_bounds__(512,4) void k_agg(
    const u16* __restrict__ msg, const u16* __restrict__ Wt,
    float* __restrict__ agg){
  __shared__ __align__(16) u16 sA[2][64*64];
  __shared__ __align__(16) u16 sB[2][128*64];
  const int tid = threadIdx.x;
  const int lane = tid & 63, wave = tid >> 6;
  const int wm = wave >> 2, wn = wave & 3;
  const int g = blockIdx.x;
  const int et = g & 3;              // innermost: siblings co-scheduled
  const int bv = g >> 2;
  const int b  = bv >> 4;
  const int vt = bv & 15;
  const int v0 = vt*64, e0 = et*128;
  const u16* Ab = msg + ((size_t)b*Nn + v0)*KK;
  const u16* Bb = Wt + (size_t)e0*KK;

  f32x4 acc[2][2];
  #pragma unroll
  for (int m=0;m<2;m++)
    #pragma unroll
    for (int n=0;n<2;n++) acc[m][n] = (f32x4){0.f,0.f,0.f,0.f};

  #define STAGE(buf, kt) do {                                              \
    { int c = tid; int row_ = c>>3, chg = (c&7) ^ (row_&7);                \
      gll16(Ab + (size_t)row_*KK + (kt)*64 + chg*8,                        \
            (char*)sA[buf] + ((size_t)(wave<<6))*16); }                    \
    _Pragma("unroll")                                                      \
    for (int i=0;i<2;i++){                                                 \
      int c = i*512 + tid; int row_ = c>>3, chg = (c&7) ^ (row_&7);        \
      gll16(Bb + (size_t)row_*KK + (kt)*64 + chg*8,                        \
            (char*)sB[buf] + ((size_t)(i*512 + (wave<<6)))*16);            \
    }                                                                      \
  } while(0)

  STAGE(0, 0);
  __syncthreads();

  const int ch = lane >> 4, rlo = lane & 15;

  for (int kt = 0; kt < KK/64; ++kt){
    if (kt < KK/64 - 1) STAGE((kt+1)&1, kt+1);
    const char* a  = (const char*)sA[kt&1];
    const char* bb = (const char*)sB[kt&1];
    #pragma unroll
    for (int kk=0; kk<2; ++kk){
      bf16x8 af[2], bfx[2];
      #pragma unroll
      for (int m=0;m<2;m++){
        const int row = wm*32 + m*16 + rlo;
        af[m] = *(const bf16x8*)(a + row*128 + ((((kk<<2)+ch) ^ (row&7))<<4));
      }
      #pragma unroll
      for (int n=0;n<2;n++){
        const int row = wn*32 + n*16 + rlo;
        bfx[n] = *(const bf16x8*)(bb + row*128 + ((((kk<<2)+ch) ^ (row&7))<<4));
      }
      #pragma unroll
      for (int m=0;m<2;m++)
        #pragma unroll
        for (int n=0;n<2;n++)
          acc[m][n] = __builtin_amdgcn_mfma_f32_16x16x32_bf16(af[m], bfx[n], acc[m][n], 0, 0, 0);
    }
    __syncthreads();
  }
  #undef STAGE

  float* ob = agg + ((size_t)b*Nn + v0)*Dd + e0;
  #pragma unroll
  for (int m=0;m<2;m++)
    #pragma unroll
    for (int reg=0;reg<4;reg++){
      const int row = wm*32 + m*16 + ((lane>>4)<<2) + reg;
      #pragma unroll
      for (int n=0;n<2;n++){
        const int col = wn*32 + n*16 + (lane & 15);
        ob[(size_t)row*Dd + col] = acc[m][n][reg];
      }
    }
}

// ---------------- K4: out = LN(relu(agg) + h) * gamma + beta; 4 rows/block
__global__ __launch_bounds__(256,4) void k_ln(
    const float* __restrict__ agg, const float* __restrict__ h,
    const float* __restrict__ gamma, const float* __restrict__ beta,
    float* __restrict__ out){
  const int row = blockIdx.x*4 + (threadIdx.x >> 6);
  const int lane = threadIdx.x & 63;
  const float* a  = agg + (size_t)row*Dd;
  const float* hh = h   + (size_t)row*Dd;
  float x[8];
  float sum = 0.f, sq = 0.f;
  #pragma unroll
  for (int q=0;q<2;q++){
    f32x4 av = *(const f32x4*)(a  + ((size_t)q*64+lane)*4);
    f32x4 hv = *(const f32x4*)(hh + ((size_t)q*64+lane)*4);
    #pragma unroll
    for (int k=0;k<4;k++){
      float v = fmaxf(av[k], 0.f) + hv[k];
      x[q*4+k] = v; sum += v; sq += v*v;
    }
  }
  #pragma unroll
  for (int off=32; off; off>>=1){
    sum += __shfl_xor(sum, off);
    sq  += __shfl_xor(sq,  off);
  }
  const float mu  = sum * (1.f/(float)Dd);
  const float var = sq * (1.f/(float)Dd) - mu*mu;
  const float rstd = rsqrtf(var + 1e-5f);
  float* o = out + (size_t)row*Dd;
  #pragma unroll
  for (int q=0;q<2;q++){
    f32x4 g  = *(const f32x4*)(gamma + ((size_t)q*64+lane)*4);
    f32x4 be = *(const f32x4*)(beta  + ((size_t)q*64+lane)*4);
    f32x4 ov;
    #pragma unroll
    for (int k=0;k<4;k++)
      ov[k] = (x[q*4+k] - mu) * rstd * g[k] + be[k];
    *(f32x4*)(o + ((size_t)q*64+lane)*4) = ov;
  }
}

extern "C" void kernel_launch(void* const* d_in, const int* in_sizes, int n_in,
                              void* d_out, int out_size, void* d_ws, size_t ws_size,
                              hipStream_t stream){
  const float* h     = (const float*)d_in[0];
  const float* adj   = (const float*)d_in[1];
  const float* W     = (const float*)d_in[2];
  const float* gamma = (const float*)d_in[3];
  const float* beta  = (const float*)d_in[4];
  float* out = (float*)d_out;
  char* ws = (char*)d_ws;

  u16*  hTp = (u16*)(ws);                 //  8,388,608  (Bd*Dd*Nn*2)
  u16*  Wt2 = (u16*)(ws + 8388608);       //  2,621,440  (Dd*KK*2)
  u16*  msg = (u16*)(ws + 11010048);      // 41,943,040  (Bd*Nn*KK*2)
  float* agg = (float*)(ws + 52953088);   // 16,777,216  (Bd*Nn*Dd*4)

  k_prep<<<dim3(5376), dim3(256), 0, stream>>>(h, W, hTp, Wt2, msg);
  k_msg <<<dim3(Bd*32), dim3(512), 0, stream>>>(adj, hTp, msg);
  k_agg <<<dim3(Bd*(Nn/64)*(Dd/128)), dim3(512), 0, stream>>>(msg, Wt2, agg);
  k_ln  <<<dim3(Bd*Nn/4), dim3(256), 0, stream>>>(agg, h, gamma, beta, out);
}

// Round 17
// 91.730 us; speedup vs baseline: 1.3557x; 1.0383x over previous
//
#include <hip/hip_runtime.h>
#include <stdint.h>

#define Bd 8
#define Rr 5
#define Nn 1024
#define Dd 512
#define KK (Rr*Dd) /* 2560 */

typedef __attribute__((ext_vector_type(8))) short bf16x8;
typedef __attribute__((ext_vector_type(4))) float f32x4;
typedef unsigned short u16;
typedef unsigned int u32;

__device__ __forceinline__ u16 f2bf(float x){
  union { float f; unsigned u; } v; v.f = x;
  unsigned r = v.u + 0x7FFFu + ((v.u >> 16) & 1u);
  return (u16)(r >> 16);
}

__device__ __forceinline__ void gll16(const void* g, void* l){
  __builtin_amdgcn_global_load_lds(
      (const __attribute__((address_space(1))) void*)g,
      (__attribute__((address_space(3))) void*)l, 16, 0, 0);
}

// ---------------- K1: fused prep ----------------
__global__ __launch_bounds__(256) void k_prep(
    const float* __restrict__ h, const float* __restrict__ W,
    u16* __restrict__ hTp, u16* __restrict__ Wt2, u16* __restrict__ msg){
  __shared__ float t32[32][65];
  const int tid = threadIdx.x;
  const int g = blockIdx.x;
  if (g < 2048){
    const int ut  = g & 31;
    const int dtg = (g >> 5) & 7;
    const int b   = g >> 8;
    const float* hb = h + ((size_t)b*Nn + (size_t)ut*32)*Dd + dtg*64;
    #pragma unroll
    for (int j=0;j<8;j++){
      int e = j*256 + tid;
      int ul = e >> 6, dl = e & 63;
      t32[ul][dl] = hb[(size_t)ul*Dd + dl];
    }
    __syncthreads();
    u16* ob = hTp + (size_t)b*Dd*Nn;
    #pragma unroll
    for (int j=0;j<8;j++){
      int e = j*256 + tid;
      int dtl = e >> 9;
      int rem = e & 511;
      int dr = rem >> 5, uu = rem & 31;
      int dt = dtg*4 + dtl;
      ob[((size_t)ut*32 + dt)*512 + rem] = f2bf(t32[uu][dtl*16 + dr]);
    }
  } else if (g < 3328){
    int idx = (g - 2048)*1024 + tid*4;     // over 512*2560
    int e = idx / KK;
    int k = idx % KK;
    int ri = (k < 2048) ? (1 + (k >> 9)) : 0;
    int d = k & 511;
    f32x4 w = *(const f32x4*)(W + (((size_t)ri*Dd + e)*Dd + d));
    u16 o[4] = { f2bf(w.x), f2bf(w.y), f2bf(w.z), f2bf(w.w) };
    *(uint2*)(Wt2 + idx) = *(uint2*)o;
  } else {
    int q = g - 3328;                      // 0..2047
    int row = q*4 + (tid >> 6);
    int d0 = (tid & 63)*8;
    f32x4 a = *(const f32x4*)(h + (size_t)row*Dd + d0);
    f32x4 c = *(const f32x4*)(h + (size_t)row*Dd + d0 + 4);
    bf16x8 pk;
    pk[0]=(short)f2bf(a.x); pk[1]=(short)f2bf(a.y);
    pk[2]=(short)f2bf(a.z); pk[3]=(short)f2bf(a.w);
    pk[4]=(short)f2bf(c.x); pk[5]=(short)f2bf(c.y);
    pk[6]=(short)f2bf(c.z); pk[7]=(short)f2bf(c.w);
    *(bf16x8*)(msg + (size_t)row*KK + 2048 + d0) = pk;
  }
}

// ---------------- K2: r-fused msg, cross-barrier B prefetch (R9 verbatim) ----
// msg[b][v][(r-1)*512+d] = (1/deg) * sum_u adj[b,r,v,u] h[b,u,d]
// BM=32, BN=512, BK=64, 16 steps, grid 256 (1 block/CU), 512 thr = 8 waves.
__global__ __launch_bounds__(512,2) void k_msg(
    const float* __restrict__ adj, const u16* __restrict__ hTp,
    u16* __restrict__ msg){
  __shared__ __align__(16) u16 sA[2][4][32*64];   // 32KB double-buffered adj
  __shared__ float sT[16*516];                    // 33KB epilogue transpose
  __shared__ float sDeg[4][32];

  const int tid  = threadIdx.x;
  const int lane = tid & 63;
  const int wave = tid >> 6;
  const int b  = blockIdx.x & 7;     // b -> XCD (L2 locality for hTp[b])
  const int vt = blockIdx.x >> 3;
  const int v0 = vt * 32;
  const int t0 = blockIdx.x & 15;    // stagger
  const float* adjb = adj + (((size_t)b*Rr + 1)*Nn + v0)*Nn;  // r=1 base
  const u16* hTpb = hTp + (size_t)b*Dd*Nn;

  const int srow = tid >> 4;         // 0..31
  const int sc   = tid & 15;         // 16B chunk
  const size_t aoff = (size_t)srow*Nn + sc*4;
  const int wslot = sc ^ ((srow & 7) << 1);

  float deg[4] = {0.f,0.f,0.f,0.f};
  f32x4 areg[4];
  f32x4 acc[4][2][4];
  #pragma unroll
  for (int ri=0;ri<4;ri++)
    #pragma unroll
    for (int m=0;m<2;m++)
      #pragma unroll
      for (int n=0;n<4;n++) acc[ri][m][n] = (f32x4){0.f,0.f,0.f,0.f};

  const int rlo = lane & 15, ch = lane >> 4;
  const int boff = rlo*32 + ch*8;

  #define TT(x) (((x) + t0) & 15)

  #define AISSUE(T) do {                                                      \
    _Pragma("unroll")                                                         \
    for (int ri=0;ri<4;ri++)                                                  \
      areg[ri] = *(const f32x4*)(adjb + (size_t)ri*Nn*Nn + (size_t)(T)*64 + aoff); \
  } while(0)

  #define PACK(BUFI) do {                                                     \
    _Pragma("unroll")                                                         \
    for (int ri=0;ri<4;ri++){                                                 \
      f32x4 p = areg[ri];                                                     \
      deg[ri] += p.x+p.y+p.z+p.w;                                             \
      uint2 pk;  /* adj in {0,1}: truncation exact */                         \
      pk.x = (__float_as_uint(p.x)>>16) | (__float_as_uint(p.y) & 0xFFFF0000u);\
      pk.y = (__float_as_uint(p.z)>>16) | (__float_as_uint(p.w) & 0xFFFF0000u);\
      *(uint2*)((char*)sA[BUFI][ri] + srow*128 + wslot*8) = pk;               \
    }                                                                         \
  } while(0)

  #define LOADB(T) do {                                                      \
    _Pragma("unroll")                                                         \
    for (int kk=0;kk<2;kk++){                                                 \
      const u16* bp = hTpb + ((((size_t)((T)*2+kk))*32 + (wave<<2))<<9) + boff;\
      _Pragma("unroll")                                                       \
      for (int n=0;n<4;n++)                                                   \
        bfr[kk][n] = *(const bf16x8*)(bp + ((size_t)n<<9));                   \
    }                                                                         \
  } while(0)

  #define MSTEP(BUFI) do {                                                    \
    const char* abase = (const char*)sA[BUFI];                                \
    _Pragma("unroll")                                                         \
    for (int kk=0;kk<2;kk++){                                                 \
      _Pragma("unroll")                                                       \
      for (int ri=0;ri<4;ri++){                                               \
        bf16x8 af[2];                                                         \
        _Pragma("unroll")                                                     \
        for (int m=0;m<2;m++){                                                \
          const int row = m*16 + rlo;                                         \
          af[m] = *(const bf16x8*)(abase + ri*4096 + row*128                  \
                    + (((kk*8 + ch*2) ^ ((row&7)<<1))<<3));                   \
        }                                                                     \
        _Pragma("unroll")                                                     \
        for (int m=0;m<2;m++)                                                 \
          _Pragma("unroll")                                                   \
          for (int n=0;n<4;n++)                                               \
            acc[ri][m][n] = __builtin_amdgcn_mfma_f32_16x16x32_bf16(          \
                af[m], bfr[kk][n], acc[ri][m][n], 0, 0, 0);                   \
      }                                                                       \
    }                                                                         \
  } while(0)

  #define FENCE() __builtin_amdgcn_sched_barrier(0)
  #define STEP_BARRIER() do {                                                 \
    asm volatile("s_waitcnt lgkmcnt(0)" ::: "memory");                        \
    FENCE();                                                                  \
    __builtin_amdgcn_s_barrier();                                             \
    FENCE();                                                                  \
  } while(0)

  bf16x8 bfr[2][4];

  // prologue: pack tile TT(0) -> buf0; B(TT(0)) oldest in FIFO; adj(TT(1)) next
  AISSUE(TT(0));
  PACK(0);
  __syncthreads();
  LOADB(TT(0));
  FENCE();
  AISSUE(TT(1));
  FENCE();

  for (int t = 0; t < 15; ++t){
    PACK((t+1)&1);             // consumes adj(t+1); vmcnt wait leaves B in flight
    FENCE();
    if (t < 14) AISSUE(TT(t+2));  // adj(t+2): ~1 full step in flight
    FENCE();
    MSTEP(t&1);                // bfr loaded last step: no exposed B wait
    FENCE();
    LOADB(TT(t+1));            // B(t+1) crosses the barrier in registers
    STEP_BARRIER();
  }
  MSTEP(1);                    // t = 15
  #undef TT
  #undef AISSUE
  #undef PACK
  #undef LOADB
  #undef MSTEP
  #undef FENCE
  #undef STEP_BARRIER

  // deg reduce over the 16 threads sharing srow
  #pragma unroll
  for (int ri=0;ri<4;ri++){
    float d = deg[ri];
    d += __shfl_xor(d, 1); d += __shfl_xor(d, 2);
    d += __shfl_xor(d, 4); d += __shfl_xor(d, 8);
    if (sc == 0) sDeg[ri][srow] = d;
  }
  __syncthreads();

  // Epilogue: per (ri, half): scale -> swizzled sT -> dense 1KB-row stores
  u16* mb = msg + ((size_t)b*Nn + v0)*KK;
  #pragma unroll
  for (int ri=0;ri<4;ri++){
    #pragma unroll
    for (int hh=0;hh<2;hh++){
      #pragma unroll
      for (int reg=0;reg<4;reg++){
        const int rl = ch*4 + reg;
        const float inv = 1.0f / fmaxf(sDeg[ri][hh*16 + rl], 1.0f);
        #pragma unroll
        for (int n=0;n<4;n++){
          const int col = (wave<<6) + n*16 + rlo;
          const int colw = col ^ (((col>>5)&7)<<2);
          sT[rl*516 + colw] = acc[ri][hh][n][reg] * inv;
        }
      }
      __syncthreads();
      #pragma unroll
      for (int s=0;s<2;s++){
        const int rl = wave*2 + s;
        const int m5 = lane >> 2;
        const int e  = m5 & 7;
        const int j0 = (2*lane) & 7;
        f32x4 lo = *(const f32x4*)&sT[rl*516 + (m5<<5) + (((j0  ) ^ e)<<2)];
        f32x4 hi = *(const f32x4*)&sT[rl*516 + (m5<<5) + (((j0+1) ^ e)<<2)];
        bf16x8 pk;
        pk[0]=(short)f2bf(lo.x); pk[1]=(short)f2bf(lo.y);
        pk[2]=(short)f2bf(lo.z); pk[3]=(short)f2bf(lo.w);
        pk[4]=(short)f2bf(hi.x); pk[5]=(short)f2bf(hi.y);
        pk[6]=(short)f2bf(hi.z); pk[7]=(short)f2bf(hi.w);
        *(bf16x8*)(mb + (size_t)(hh*16 + rl)*KK + ri*512 + lane*8) = pk;
      }
      __syncthreads();
    }
  }
}

// ---------------- K3: agg[b][v][e] = sum_k msg[b][v][k] * Wt2[e][k], K=2560
// R9 decode: et outermost (best measured).
__global__ __launch_bounds__(512,4) void k_agg(
    const u16* __restrict__ msg, const u16* __restrict__ Wt,
    float* __restrict__ agg){
  __shared__ __align__(16) u16 sA[2][64*64];
  __shared__ __align__(16) u16 sB[2][128*64];
  const int tid = threadIdx.x;
  const int lane = tid & 63, wave = tid >> 6;
  const int wm = wave >> 2, wn = wave & 3;
  const int g = blockIdx.x;
  const int et = g >> 7;
  const int bv = g & 127;
  const int b  = bv >> 4;
  const int vt = bv & 15;
  const int v0 = vt*64, e0 = et*128;
  const u16* Ab = msg + ((size_t)b*Nn + v0)*KK;
  const u16* Bb = Wt + (size_t)e0*KK;

  f32x4 acc[2][2];
  #pragma unroll
  for (int m=0;m<2;m++)
    #pragma unroll
    for (int n=0;n<2;n++) acc[m][n] = (f32x4){0.f,0.f,0.f,0.f};

  #define STAGE(buf, kt) do {                                              \
    { int c = tid; int row_ = c>>3, chg = (c&7) ^ (row_&7);                \
      gll16(Ab + (size_t)row_*KK + (kt)*64 + chg*8,                        \
            (char*)sA[buf] + ((size_t)(wave<<6))*16); }                    \
    _Pragma("unroll")                                                      \
    for (int i=0;i<2;i++){                                                 \
      int c = i*512 + tid; int row_ = c>>3, chg = (c&7) ^ (row_&7);        \
      gll16(Bb + (size_t)row_*KK + (kt)*64 + chg*8,                        \
            (char*)sB[buf] + ((size_t)(i*512 + (wave<<6)))*16);            \
    }                                                                      \
  } while(0)

  STAGE(0, 0);
  __syncthreads();

  const int ch = lane >> 4, rlo = lane & 15;

  for (int kt = 0; kt < KK/64; ++kt){
    if (kt < KK/64 - 1) STAGE((kt+1)&1, kt+1);
    const char* a  = (const char*)sA[kt&1];
    const char* bb = (const char*)sB[kt&1];
    #pragma unroll
    for (int kk=0; kk<2; ++kk){
      bf16x8 af[2], bfx[2];
      #pragma unroll
      for (int m=0;m<2;m++){
        const int row = wm*32 + m*16 + rlo;
        af[m] = *(const bf16x8*)(a + row*128 + ((((kk<<2)+ch) ^ (row&7))<<4));
      }
      #pragma unroll
      for (int n=0;n<2;n++){
        const int row = wn*32 + n*16 + rlo;
        bfx[n] = *(const bf16x8*)(bb + row*128 + ((((kk<<2)+ch) ^ (row&7))<<4));
      }
      #pragma unroll
      for (int m=0;m<2;m++)
        #pragma unroll
        for (int n=0;n<2;n++)
          acc[m][n] = __builtin_amdgcn_mfma_f32_16x16x32_bf16(af[m], bfx[n], acc[m][n], 0, 0, 0);
    }
    __syncthreads();
  }
  #undef STAGE

  float* ob = agg + ((size_t)b*Nn + v0)*Dd + e0;
  #pragma unroll
  for (int m=0;m<2;m++)
    #pragma unroll
    for (int reg=0;reg<4;reg++){
      const int row = wm*32 + m*16 + ((lane>>4)<<2) + reg;
      #pragma unroll
      for (int n=0;n<2;n++){
        const int col = wn*32 + n*16 + (lane & 15);
        ob[(size_t)row*Dd + col] = acc[m][n][reg];
      }
    }
}

// ---------------- K4: out = LN(relu(agg) + h) * gamma + beta; 4 rows/block
__global__ __launch_bounds__(256,4) void k_ln(
    const float* __restrict__ agg, const float* __restrict__ h,
    const float* __restrict__ gamma, const float* __restrict__ beta,
    float* __restrict__ out){
  const int row = blockIdx.x*4 + (threadIdx.x >> 6);
  const int lane = threadIdx.x & 63;
  const float* a  = agg + (size_t)row*Dd;
  const float* hh = h   + (size_t)row*Dd;
  float x[8];
  float sum = 0.f, sq = 0.f;
  #pragma unroll
  for (int q=0;q<2;q++){
    f32x4 av = *(const f32x4*)(a  + ((size_t)q*64+lane)*4);
    f32x4 hv = *(const f32x4*)(hh + ((size_t)q*64+lane)*4);
    #pragma unroll
    for (int k=0;k<4;k++){
      float v = fmaxf(av[k], 0.f) + hv[k];
      x[q*4+k] = v; sum += v; sq += v*v;
    }
  }
  #pragma unroll
  for (int off=32; off; off>>=1){
    sum += __shfl_xor(sum, off);
    sq  += __shfl_xor(sq,  off);
  }
  const float mu  = sum * (1.f/(float)Dd);
  const float var = sq * (1.f/(float)Dd) - mu*mu;
  const float rstd = rsqrtf(var + 1e-5f);
  float* o = out + (size_t)row*Dd;
  #pragma unroll
  for (int q=0;q<2;q++){
    f32x4 g  = *(const f32x4*)(gamma + ((size_t)q*64+lane)*4);
    f32x4 be = *(const f32x4*)(beta  + ((size_t)q*64+lane)*4);
    f32x4 ov;
    #pragma unroll
    for (int k=0;k<4;k++)
      ov[k] = (x[q*4+k] - mu) * rstd * g[k] + be[k];
    *(f32x4*)(o + ((size_t)q*64+lane)*4) = ov;
  }
}

extern "C" void kernel_launch(void* const* d_in, const int* in_sizes, int n_in,
                              void* d_out, int out_size, void* d_ws, size_t ws_size,
                              hipStream_t stream){
  const float* h     = (const float*)d_in[0];
  const float* adj   = (const float*)d_in[1];
  const float* W     = (const float*)d_in[2];
  const float* gamma = (const float*)d_in[3];
  const float* beta  = (const float*)d_in[4];
  float* out = (float*)d_out;
  char* ws = (char*)d_ws;

  u16*  hTp = (u16*)(ws);                 //  8,388,608  (Bd*Dd*Nn*2)
  u16*  Wt2 = (u16*)(ws + 8388608);       //  2,621,440  (Dd*KK*2)
  u16*  msg = (u16*)(ws + 11010048);      // 41,943,040  (Bd*Nn*KK*2)
  float* agg = (float*)(ws + 52953088);   // 16,777,216  (Bd*Nn*Dd*4)

  k_prep<<<dim3(5376), dim3(256), 0, stream>>>(h, W, hTp, Wt2, msg);
  k_msg <<<dim3(Bd*32), dim3(512), 0, stream>>>(adj, hTp, msg);
  k_agg <<<dim3(Bd*(Nn/64)*(Dd/128)), dim3(512), 0, stream>>>(msg, Wt2, agg);
  k_ln  <<<dim3(Bd*Nn/4), dim3(256), 0, stream>>>(agg, h, gamma, beta, out);
}